// Round 2
// baseline (285.284 us; speedup 1.0000x reference)
//
#include <hip/hip_runtime.h>

#define BATCH 16
#define C_IN  64
#define HH    64
#define WW    64
#define COUT  64
#define KK    9
#define HW    (HH * WW)     // 4096
#define CK    (C_IN * KK)   // 576

// Transpose weight (Cout, C, 3, 3) -> Wt[ck][o] so the o-run for a fixed
// (c,k) is contiguous and scalar-loadable.
__global__ void transpose_w_kernel(const float* __restrict__ w,
                                   float* __restrict__ wt) {
    int i = blockIdx.x * 256 + threadIdx.x;  // 0 .. CK*COUT-1 (36864, exact)
    int ck = i >> 6;
    int o  = i & 63;
    wt[i] = w[o * CK + ck];
}

// Block = 256 thr = 4 waves, covering 64 pixels (one image row) x 64 cout.
//   wave w: o-half = w&1 (32 couts), c-half = w>>1 (32 channels).
// c-half 1 waves dump partial acc to LDS; c-half 0 waves add + store.
// Grid = 16 images * 64 rows = 1024 blocks; blockIdx swizzled so each XCD
// (blk % 8 under round-robin dispatch) owns 2 images -> x stays L2-resident
// across all 9 kernel taps (fix for the 261 MB HBM over-fetch seen in R1).
__global__ __launch_bounds__(256) void dcn_fwd_kernel(
    const float* __restrict__ x, const float* __restrict__ offset,
    const float* __restrict__ mask, const float* __restrict__ wt,
    const float* __restrict__ bias, float* __restrict__ out) {
    __shared__ float red[2][64][33];  // [o-half][px][o], +1 pad -> 2-way max

    const int t    = threadIdx.x;
    const int wave = __builtin_amdgcn_readfirstlane(t >> 6);
    const int ohalf = wave & 1;
    const int chalf = wave >> 1;
    const int obase = ohalf * 32;
    const int cbase = chalf * 32;
    const int lane  = t & 63;

    const int blk = blockIdx.x;
    const int xcd = blk & 7;
    const int j   = blk >> 3;                 // 0..127
    const int b   = (xcd << 1) | (j >> 6);    // 2 images per XCD
    const int row = j & 63;
    const int pix = (row << 6) | lane;
    const int p = row, q = lane;

    float acc[32];
#pragma unroll
    for (int o = 0; o < 32; ++o) acc[o] = 0.f;

    const float* xb  = x + b * (C_IN * HW) + cbase * HW;
    const int offb = b * (2 * KK * HW);
    const int mb   = b * (KK * HW);

    for (int k = 0; k < KK; ++k) {
        const int ky = k / 3, kx = k % 3;
        const float oy = offset[offb + (2 * k)     * HW + pix];
        const float ox = offset[offb + (2 * k + 1) * HW + pix];
        const float mk = mask[mb + k * HW + pix];

        const float py = oy + (float)(p - 1 + ky);
        const float px = ox + (float)(q - 1 + kx);
        const float y0f = floorf(py), x0f = floorf(px);
        const float wy = py - y0f, wx = px - x0f;
        const int y0 = (int)y0f, x0 = (int)x0f;
        const int y1 = y0 + 1,   x1 = x0 + 1;

        const float vy0 = (y0 >= 0 && y0 < HH) ? 1.f : 0.f;
        const float vy1 = (y1 >= 0 && y1 < HH) ? 1.f : 0.f;
        const float vx0 = (x0 >= 0 && x0 < WW) ? 1.f : 0.f;
        const float vx1 = (x1 >= 0 && x1 < WW) ? 1.f : 0.f;

        const float w00 = (1.f - wy) * (1.f - wx) * vy0 * vx0 * mk;
        const float w01 = (1.f - wy) * wx         * vy0 * vx1 * mk;
        const float w10 = wy * (1.f - wx)         * vy1 * vx0 * mk;
        const float w11 = wy * wx                 * vy1 * vx1 * mk;

        const int cy0 = min(max(y0, 0), HH - 1), cy1 = min(max(y1, 0), HH - 1);
        const int cx0 = min(max(x0, 0), WW - 1), cx1 = min(max(x1, 0), WW - 1);
        const int a00 = cy0 * WW + cx0, a01 = cy0 * WW + cx1;
        const int a10 = cy1 * WW + cx0, a11 = cy1 * WW + cx1;

#pragma unroll 2
        for (int c = 0; c < 32; ++c) {
            const float* plane = xb + c * HW;
            const float v = w00 * plane[a00] + w01 * plane[a01] +
                            w10 * plane[a10] + w11 * plane[a11];
            // wave-uniform address -> scalar loads, dual-issue with FMAs
            const float* wrow = wt + ((cbase + c) * KK + k) * COUT + obase;
#pragma unroll
            for (int o = 0; o < 32; ++o) acc[o] = fmaf(v, wrow[o], acc[o]);
        }
    }

    if (chalf == 1) {
#pragma unroll
        for (int o = 0; o < 32; ++o) red[ohalf][lane][o] = acc[o];
    }
    __syncthreads();
    if (chalf == 0) {
        float* ob = out + b * (COUT * HW) + obase * HW + pix;
#pragma unroll
        for (int o = 0; o < 32; ++o)
            ob[o * HW] = acc[o] + red[ohalf][lane][o] + bias[obase + o];
    }
}

extern "C" void kernel_launch(void* const* d_in, const int* in_sizes, int n_in,
                              void* d_out, int out_size, void* d_ws,
                              size_t ws_size, hipStream_t stream) {
    const float* x    = (const float*)d_in[0];
    const float* off  = (const float*)d_in[1];
    const float* mask = (const float*)d_in[2];
    const float* w    = (const float*)d_in[3];
    const float* bias = (const float*)d_in[4];
    float* out = (float*)d_out;
    float* wt  = (float*)d_ws;  // CK*COUT floats = 147456 B

    transpose_w_kernel<<<(CK * COUT) / 256, 256, 0, stream>>>(w, wt);
    dcn_fwd_kernel<<<BATCH * HH, 256, 0, stream>>>(x, off, mask, wt, bias, out);
}

// Round 3
// 136.256 us; speedup vs baseline: 2.0937x; 2.0937x over previous
//
#include <hip/hip_runtime.h>

#define BATCH 16
#define C_IN  64
#define HH    64
#define WW    64
#define COUT  64
#define KK    9
#define HW    (HH * WW)     // 4096
#define CK    (C_IN * KK)   // 576
#define MROW  200           // 192 data + 8 pad ushorts -> balanced LDS banks

typedef __bf16 bf16x8 __attribute__((ext_vector_type(8)));
typedef float  f32x4  __attribute__((ext_vector_type(4)));

__device__ __forceinline__ unsigned short f32_to_bf16_rne(float f) {
    unsigned int b = __float_as_uint(f);
    b += 0x7FFFu + ((b >> 16) & 1u);
    return (unsigned short)(b >> 16);
}

// x (B,C,H,W) fp32 -> xt (B,H,W,C) bf16.  One block per (b,y) row.
__global__ __launch_bounds__(256) void transpose_x_kernel(
    const float* __restrict__ x, unsigned short* __restrict__ xt) {
    __shared__ unsigned short tile[64][66];  // [xcol][c], +2 pad -> no bank pileup
    const int t = threadIdx.x;
    const int b = blockIdx.x >> 6;
    const int y = blockIdx.x & 63;
    const int c0 = t >> 6, xcol = t & 63;
#pragma unroll
    for (int it = 0; it < 16; ++it) {
        const int c = c0 + it * 4;
        tile[xcol][c] = f32_to_bf16_rne(x[((b * 64 + c) * 64 + y) * 64 + xcol]);
    }
    __syncthreads();
#pragma unroll
    for (int it = 0; it < 16; ++it) {
        const int pos = it * 256 + t;
        const int xx = pos >> 6, c = pos & 63;
        xt[((b * 4096) + y * 64 + xx) * 64 + c] = tile[xx][c];
    }
}

// w (Cout, C, 3, 3) fp32 -> wt[o][k*64 + c] bf16.
__global__ void prep_w_kernel(const float* __restrict__ w,
                              unsigned short* __restrict__ wt) {
    const int i = blockIdx.x * 256 + threadIdx.x;  // 0..36863
    const int o = i / CK;
    const int r = i - o * CK;
    const int k = r >> 6, c = r & 63;
    wt[i] = f32_to_bf16_rne(w[o * CK + c * KK + k]);
}

// Main: block = 256 thr = 4 waves, covers one image row (64 px) x 64 cout.
// 3 chunks of 3 taps:  params -> channels-last sampling into LDS (bf16)
// -> 16x16x32 bf16 MFMA.  XCD swizzle pins 2 images per XCD L2 (R2 win).
__global__ __launch_bounds__(256) void dcn_main_kernel(
    const float* __restrict__ offset, const float* __restrict__ mask,
    const unsigned short* __restrict__ xt, const unsigned short* __restrict__ wt,
    const float* __restrict__ bias, float* __restrict__ out) {
    __shared__ __align__(16) unsigned short Mlds[64 * MROW];  // 25600 B
    __shared__ __align__(16) int Plds[3 * 64 * 8];            // 6144 B

    const int t    = threadIdx.x;
    const int wave = __builtin_amdgcn_readfirstlane(t >> 6);
    const int lane = t & 63;

    const int blk = blockIdx.x;
    const int xcd = blk & 7;
    const int j   = blk >> 3;
    const int b   = (xcd << 1) | (j >> 6);
    const int row = j & 63;

    f32x4 acc[4];
#pragma unroll
    for (int ot = 0; ot < 4; ++ot)
#pragma unroll
        for (int r = 0; r < 4; ++r) acc[ot][r] = 0.f;

    const float* offb = offset + b * (2 * KK * HW) + row * 64;
    const float* mb   = mask + b * (KK * HW) + row * 64;
    const unsigned short* xtb = xt + b * (HW * 64);
    const int quad = lane >> 4, m16 = lane & 15;

    for (int kc = 0; kc < 3; ++kc) {
        // ---- Phase A: per-(pixel,tap) params; lane = pixel, wave = tap ----
        if (wave < 3) {
            const int ky = kc, kx = wave;       // k = kc*3 + wave
            const int k  = kc * 3 + wave;
            const int q  = lane;
            const float oy = offb[(2 * k) * HW + q];
            const float ox = offb[(2 * k + 1) * HW + q];
            const float mk = mb[k * HW + q];
            const float py = oy + (float)(row - 1 + ky);
            const float px = ox + (float)(q - 1 + kx);
            const float y0f = floorf(py), x0f = floorf(px);
            const float wy = py - y0f, wx = px - x0f;
            const int y0 = (int)y0f, x0 = (int)x0f;
            const int y1 = y0 + 1,   x1 = x0 + 1;
            const float vy0 = (y0 >= 0 && y0 < HH) ? 1.f : 0.f;
            const float vy1 = (y1 >= 0 && y1 < HH) ? 1.f : 0.f;
            const float vx0 = (x0 >= 0 && x0 < WW) ? 1.f : 0.f;
            const float vx1 = (x1 >= 0 && x1 < WW) ? 1.f : 0.f;
            const float w00 = (1.f - wy) * (1.f - wx) * vy0 * vx0 * mk;
            const float w01 = (1.f - wy) * wx         * vy0 * vx1 * mk;
            const float w10 = wy * (1.f - wx)         * vy1 * vx0 * mk;
            const float w11 = wy * wx                 * vy1 * vx1 * mk;
            const int cy0 = min(max(y0, 0), HH - 1), cy1 = min(max(y1, 0), HH - 1);
            const int cx0 = min(max(x0, 0), WW - 1), cx1 = min(max(x1, 0), WW - 1);
            int* P = &Plds[(wave * 64 + q) * 8];
            P[0] = __float_as_int(w00); P[1] = __float_as_int(w01);
            P[2] = __float_as_int(w10); P[3] = __float_as_int(w11);
            P[4] = (cy0 * 64 + cx0) * 64; P[5] = (cy0 * 64 + cx1) * 64;
            P[6] = (cy1 * 64 + cx0) * 64; P[7] = (cy1 * 64 + cx1) * 64;
        }
        __syncthreads();

        // ---- Phase B: sampling.  lane = channel; iterate (tap,pixel) ----
#pragma unroll 2
        for (int i = 0; i < 48; ++i) {
            const int pi  = wave * 48 + i;       // 0..191 = tap*64 + pixel
            const int tap = pi >> 6;
            const int pxl = pi & 63;
            const int4 p0 = *(const int4*)&Plds[pi * 8];
            const int4 p1 = *(const int4*)&Plds[pi * 8 + 4];
            const unsigned short u00 = xtb[p1.x + lane];
            const unsigned short u01 = xtb[p1.y + lane];
            const unsigned short u10 = xtb[p1.z + lane];
            const unsigned short u11 = xtb[p1.w + lane];
            float v;
            v = __int_as_float(p0.x) * __uint_as_float((unsigned)u00 << 16);
            v = fmaf(__int_as_float(p0.y), __uint_as_float((unsigned)u01 << 16), v);
            v = fmaf(__int_as_float(p0.z), __uint_as_float((unsigned)u10 << 16), v);
            v = fmaf(__int_as_float(p0.w), __uint_as_float((unsigned)u11 << 16), v);
            Mlds[pxl * MROW + tap * 64 + lane] = f32_to_bf16_rne(v);
        }
        __syncthreads();

        // ---- Phase C: MFMA.  wave = 16-pixel strip; A=W[o][ck], B=M^T ----
        const unsigned short* wbase = wt + kc * 192;
#pragma unroll
        for (int ks = 0; ks < 6; ++ks) {
            const bf16x8 bfrag = *(const bf16x8*)&Mlds[(wave * 16 + m16) * MROW +
                                                       ks * 32 + quad * 8];
#pragma unroll
            for (int ot = 0; ot < 4; ++ot) {
                const bf16x8 afrag = *(const bf16x8*)&wbase[(ot * 16 + m16) * CK +
                                                            ks * 32 + quad * 8];
                acc[ot] = __builtin_amdgcn_mfma_f32_16x16x32_bf16(afrag, bfrag,
                                                                  acc[ot], 0, 0, 0);
            }
        }
        __syncthreads();
    }

    // ---- Epilogue: D[m=o][n=pixel]; o = ot*16 + quad*4 + r ----
    float* ob = out + b * (COUT * HW) + row * 64 + wave * 16 + m16;
#pragma unroll
    for (int ot = 0; ot < 4; ++ot)
#pragma unroll
        for (int r = 0; r < 4; ++r) {
            const int o = ot * 16 + quad * 4 + r;
            ob[o * HW] = acc[ot][r] + bias[o];
        }
}

extern "C" void kernel_launch(void* const* d_in, const int* in_sizes, int n_in,
                              void* d_out, int out_size, void* d_ws,
                              size_t ws_size, hipStream_t stream) {
    const float* x    = (const float*)d_in[0];
    const float* off  = (const float*)d_in[1];
    const float* mask = (const float*)d_in[2];
    const float* w    = (const float*)d_in[3];
    const float* bias = (const float*)d_in[4];
    float* out = (float*)d_out;

    unsigned short* xt = (unsigned short*)d_ws;                  // 8388608 B
    unsigned short* wt = (unsigned short*)((char*)d_ws + 8388608);  // 73728 B

    transpose_x_kernel<<<BATCH * HH, 256, 0, stream>>>(x, xt);
    prep_w_kernel<<<(COUT * CK) / 256, 256, 0, stream>>>(w, wt);
    dcn_main_kernel<<<BATCH * HH, 256, 0, stream>>>(off, mask, xt, wt, bias, out);
}

// Round 4
// 129.247 us; speedup vs baseline: 2.2073x; 1.0542x over previous
//
#include <hip/hip_runtime.h>

#define BATCH 16
#define C_IN  64
#define HH    64
#define WW    64
#define COUT  64
#define KK    9
#define HW    4096
#define CK    576
#define MROW  200   // 192 data ushorts + 8 pad; row stride 400 B (16-B aligned)

typedef __bf16 bf16x8 __attribute__((ext_vector_type(8)));
typedef float  f32x4  __attribute__((ext_vector_type(4)));

__device__ __forceinline__ unsigned int f32_to_bf16_rne(float f) {
    unsigned int b = __float_as_uint(f);
    b += 0x7FFFu + ((b >> 16) & 1u);
    return b >> 16;  // low 16 bits valid
}

// Fused prep.  Blocks 0..1023: x (B,C,H,W) f32 -> xt (B,H,W,C) bf16, one
// block per (b,y), vectorized dwordx4 both global sides.  Blocks 1024..1167:
// w (Cout,C,3,3) f32 -> wt[o][k*64+c] bf16.
__global__ __launch_bounds__(256) void prep_kernel(
    const float* __restrict__ x, const float* __restrict__ w,
    unsigned short* __restrict__ xt, unsigned short* __restrict__ wt) {
    __shared__ unsigned short tile[64][72];  // [x-col][c]; 144-B rows (16-B ok)
    const int t = threadIdx.x;
    const int blk = blockIdx.x;
    if (blk < 1024) {
        const int b = blk >> 6, y = blk & 63;
        const float* xrow = x + ((b * 64) * 64 + y) * 64;
#pragma unroll
        for (int it = 0; it < 4; ++it) {
            const int idx = it * 256 + t;
            const int c = idx >> 4, seg = idx & 15;
            const float4 v = *(const float4*)(xrow + c * HW + seg * 4);
            tile[seg * 4 + 0][c] = (unsigned short)f32_to_bf16_rne(v.x);
            tile[seg * 4 + 1][c] = (unsigned short)f32_to_bf16_rne(v.y);
            tile[seg * 4 + 2][c] = (unsigned short)f32_to_bf16_rne(v.z);
            tile[seg * 4 + 3][c] = (unsigned short)f32_to_bf16_rne(v.w);
        }
        __syncthreads();
#pragma unroll
        for (int it = 0; it < 2; ++it) {
            const int idx = it * 256 + t;
            const int xx = idx >> 3, cs = idx & 7;
            *(int4*)&xt[((b * HW) + y * 64 + xx) * 64 + cs * 8] =
                *(const int4*)&tile[xx][cs * 8];
        }
    } else {
        const int i = (blk - 1024) * 256 + t;  // 0..36863
        const int o = i / CK;
        const int r = i - o * CK;
        const int k = r >> 6, c = r & 63;
        wt[i] = (unsigned short)f32_to_bf16_rne(w[o * CK + c * KK + k]);
    }
}

// Main.  Block = 128 thr = 2 waves; each wave owns a 16-px strip of one row
// x all 64 cout, fully wave-private (Plds/Mlds regions per wave) -> NO
// __syncthreads in the whole kernel; same-wave LDS ordering via lgkmcnt.
// Per chunk (3 taps): A) lanes 0-47 compute tap params -> Plds;
// B) 12 iters, quarter-wave per item: dwordx2 channels-last gathers,
// bilinear, pack bf16x2 -> Mlds;  C) 24 MFMA (4 o-tiles x 6 K-steps).
// Grid 2048, XCD swizzle pins 2 images per XCD L2 (R2 win).
__global__ __launch_bounds__(128, 4) void dcn_main_kernel(
    const float* __restrict__ offset, const float* __restrict__ mask,
    const unsigned short* __restrict__ xt, const unsigned short* __restrict__ wt,
    const float* __restrict__ bias, float* __restrict__ out) {
    __shared__ __align__(16) unsigned short Mlds[2][16 * MROW];  // 2 x 6400 B
    __shared__ __align__(16) int Plds[2][48 * 8];                // 2 x 1536 B

    const int t    = threadIdx.x;
    const int wave = __builtin_amdgcn_readfirstlane(t >> 6);
    const int lane = t & 63;
    const int quad = lane >> 4, m16 = lane & 15;

    const int blk = blockIdx.x;
    const int xcd = blk & 7;
    const int j   = blk >> 3;                  // 0..255
    const int b   = (xcd << 1) | (j >> 7);     // 2 images per XCD
    const int rr  = j & 127;
    const int row = rr >> 1;
    const int qbase = (rr & 1) * 32 + wave * 16;  // column base of this strip

    f32x4 acc[4];
#pragma unroll
    for (int ot = 0; ot < 4; ++ot)
#pragma unroll
        for (int r = 0; r < 4; ++r) acc[ot][r] = 0.f;

    const float* offb = offset + b * (2 * KK * HW) + row * 64;
    const float* mb   = mask + b * (KK * HW) + row * 64;
    const char* xtb   = (const char*)(xt + b * (HW * 64));
    int* PW = Plds[wave];
    char* MW = (char*)Mlds[wave];

    for (int kc = 0; kc < 3; ++kc) {
        // ---- Phase A: params for this wave's 48 (tap,px) items ----
        if (lane < 48) {
            const int tap = lane >> 4, pxi = lane & 15;
            const int k = kc * 3 + tap;
            const int q = qbase + pxi;
            const float oy = offb[(2 * k) * HW + q];
            const float ox = offb[(2 * k + 1) * HW + q];
            const float mk = mb[k * HW + q];
            const float py  = oy + (float)(row - 1 + kc);
            const float pxf = ox + (float)(q - 1 + tap);
            const float y0f = floorf(py), x0f = floorf(pxf);
            const float wy = py - y0f, wx = pxf - x0f;
            const int y0 = (int)y0f, x0 = (int)x0f;
            const int y1 = y0 + 1,   x1 = x0 + 1;
            const float vy0 = (y0 >= 0 && y0 < HH) ? 1.f : 0.f;
            const float vy1 = (y1 >= 0 && y1 < HH) ? 1.f : 0.f;
            const float vx0 = (x0 >= 0 && x0 < WW) ? 1.f : 0.f;
            const float vx1 = (x1 >= 0 && x1 < WW) ? 1.f : 0.f;
            const float w00 = (1.f - wy) * (1.f - wx) * vy0 * vx0 * mk;
            const float w01 = (1.f - wy) * wx         * vy0 * vx1 * mk;
            const float w10 = wy * (1.f - wx)         * vy1 * vx0 * mk;
            const float w11 = wy * wx                 * vy1 * vx1 * mk;
            const int cy0 = min(max(y0, 0), HH - 1), cy1 = min(max(y1, 0), HH - 1);
            const int cx0 = min(max(x0, 0), WW - 1), cx1 = min(max(x1, 0), WW - 1);
            int4 P0, P1;
            P0.x = __float_as_int(w00); P0.y = __float_as_int(w01);
            P0.z = __float_as_int(w10); P0.w = __float_as_int(w11);
            P1.x = (cy0 * 64 + cx0) * 128;  // byte offsets into xtb
            P1.y = (cy0 * 64 + cx1) * 128;
            P1.z = (cy1 * 64 + cx0) * 128;
            P1.w = (cy1 * 64 + cx1) * 128;
            *(int4*)(PW + lane * 8)     = P0;
            *(int4*)(PW + lane * 8 + 4) = P1;
        }

        // ---- Phase B: sample; quarter-wave (16 lanes) per item, 4 ch/lane ----
#pragma unroll 4
        for (int i = 0; i < 12; ++i) {
            const int item = i * 4 + quad;          // tap = item>>4, pxi = item&15
            const int4 p0 = *(const int4*)(PW + item * 8);
            const int4 p1 = *(const int4*)(PW + item * 8 + 4);
            const int co = m16 * 8;                 // channel byte offset (4 ch)
            const uint2 u0 = *(const uint2*)(xtb + p1.x + co);
            const uint2 u1 = *(const uint2*)(xtb + p1.y + co);
            const uint2 u2 = *(const uint2*)(xtb + p1.z + co);
            const uint2 u3 = *(const uint2*)(xtb + p1.w + co);
            const float fw00 = __int_as_float(p0.x), fw01 = __int_as_float(p0.y);
            const float fw10 = __int_as_float(p0.z), fw11 = __int_as_float(p0.w);
            float v0, v1, v2, v3;
            v0 = fw00 * __uint_as_float(u0.x << 16);
            v1 = fw00 * __uint_as_float(u0.x & 0xFFFF0000u);
            v2 = fw00 * __uint_as_float(u0.y << 16);
            v3 = fw00 * __uint_as_float(u0.y & 0xFFFF0000u);
            v0 = fmaf(fw01, __uint_as_float(u1.x << 16), v0);
            v1 = fmaf(fw01, __uint_as_float(u1.x & 0xFFFF0000u), v1);
            v2 = fmaf(fw01, __uint_as_float(u1.y << 16), v2);
            v3 = fmaf(fw01, __uint_as_float(u1.y & 0xFFFF0000u), v3);
            v0 = fmaf(fw10, __uint_as_float(u2.x << 16), v0);
            v1 = fmaf(fw10, __uint_as_float(u2.x & 0xFFFF0000u), v1);
            v2 = fmaf(fw10, __uint_as_float(u2.y << 16), v2);
            v3 = fmaf(fw10, __uint_as_float(u2.y & 0xFFFF0000u), v3);
            v0 = fmaf(fw11, __uint_as_float(u3.x << 16), v0);
            v1 = fmaf(fw11, __uint_as_float(u3.x & 0xFFFF0000u), v1);
            v2 = fmaf(fw11, __uint_as_float(u3.y << 16), v2);
            v3 = fmaf(fw11, __uint_as_float(u3.y & 0xFFFF0000u), v3);
            uint2 pk;
            pk.x = (f32_to_bf16_rne(v1) << 16) | f32_to_bf16_rne(v0);
            pk.y = (f32_to_bf16_rne(v3) << 16) | f32_to_bf16_rne(v2);
            *(uint2*)(MW + (item & 15) * 400 + (item >> 4) * 128 + m16 * 8) = pk;
        }

        // ---- Phase C: MFMA; B from private Mlds, A = wt from global/L1 ----
        const unsigned short* wc = wt + kc * 192;
#pragma unroll
        for (int ks = 0; ks < 6; ++ks) {
            const bf16x8 bfrag =
                *(const bf16x8*)(MW + m16 * 400 + ks * 64 + quad * 16);
#pragma unroll
            for (int ot = 0; ot < 4; ++ot) {
                const bf16x8 afrag = *(const bf16x8*)(wc + (ot * 16 + m16) * CK +
                                                      ks * 32 + quad * 8);
                acc[ot] = __builtin_amdgcn_mfma_f32_16x16x32_bf16(afrag, bfrag,
                                                                  acc[ot], 0, 0, 0);
            }
        }
    }

    // ---- Epilogue: D col = px = m16, row = o = ot*16 + quad*4 + r ----
    float* ob = out + b * (COUT * HW) + row * 64 + qbase + m16;
#pragma unroll
    for (int ot = 0; ot < 4; ++ot)
#pragma unroll
        for (int r = 0; r < 4; ++r) {
            const int o = ot * 16 + quad * 4 + r;
            ob[o * HW] = acc[ot][r] + bias[o];
        }
}

extern "C" void kernel_launch(void* const* d_in, const int* in_sizes, int n_in,
                              void* d_out, int out_size, void* d_ws,
                              size_t ws_size, hipStream_t stream) {
    const float* x    = (const float*)d_in[0];
    const float* off  = (const float*)d_in[1];
    const float* mask = (const float*)d_in[2];
    const float* w    = (const float*)d_in[3];
    const float* bias = (const float*)d_in[4];
    float* out = (float*)d_out;

    unsigned short* xt = (unsigned short*)d_ws;                     // 8388608 B
    unsigned short* wt = (unsigned short*)((char*)d_ws + 8388608);  // 73728 B

    prep_kernel<<<1024 + 144, 256, 0, stream>>>(x, w, xt, wt);
    dcn_main_kernel<<<2048, 128, 0, stream>>>(off, mask, xt, wt, bias, out);
}

// Round 6
// 125.858 us; speedup vs baseline: 2.2667x; 1.0269x over previous
//
#include <hip/hip_runtime.h>

#define BATCH 16
#define C_IN  64
#define HH    64
#define WW    64
#define COUT  64
#define KK    9
#define HW    4096
#define CK    576
#define MROW  200   // 192 data ushorts + 8 pad; row stride 400 B (16-B aligned)

typedef __bf16 bf16x8 __attribute__((ext_vector_type(8)));
typedef float  f32x4  __attribute__((ext_vector_type(4)));

__device__ __forceinline__ unsigned int f32_to_bf16_rne(float f) {
    unsigned int b = __float_as_uint(f);
    b += 0x7FFFu + ((b >> 16) & 1u);
    return b >> 16;  // low 16 bits valid
}

// Fused prep.  Blocks 0..1023: x (B,C,H,W) f32 -> xt (B,H,W,C) bf16.
// Blocks 1024..1167: w (Cout,C,3,3) f32 -> wt in MFMA A-fragment order:
//   wt[(((kc*6+ks)*4+ot)*64 + lane)*8 + j] = W[o=ot*16+(lane&15)]
//        [kk=ks*32+(lane>>4)*8+j] of chunk kc  (kk = tap*64+c, k=kc*3+tap)
// so phase C reads are lane-contiguous dwordx4 (coalesced, wave-uniform).
__global__ __launch_bounds__(256) void prep_kernel(
    const float* __restrict__ x, const float* __restrict__ w,
    unsigned short* __restrict__ xt, unsigned short* __restrict__ wt) {
    __shared__ unsigned short tile[64][72];
    const int t = threadIdx.x;
    const int blk = blockIdx.x;
    if (blk < 1024) {
        const int b = blk >> 6, y = blk & 63;
        const float* xrow = x + ((b * 64) * 64 + y) * 64;
#pragma unroll
        for (int it = 0; it < 4; ++it) {
            const int idx = it * 256 + t;
            const int c = idx >> 4, seg = idx & 15;
            const float4 v = *(const float4*)(xrow + c * HW + seg * 4);
            tile[seg * 4 + 0][c] = (unsigned short)f32_to_bf16_rne(v.x);
            tile[seg * 4 + 1][c] = (unsigned short)f32_to_bf16_rne(v.y);
            tile[seg * 4 + 2][c] = (unsigned short)f32_to_bf16_rne(v.z);
            tile[seg * 4 + 3][c] = (unsigned short)f32_to_bf16_rne(v.w);
        }
        __syncthreads();
#pragma unroll
        for (int it = 0; it < 2; ++it) {
            const int idx = it * 256 + t;
            const int xx = idx >> 3, cs = idx & 7;
            *(int4*)&xt[((b * HW) + y * 64 + xx) * 64 + cs * 8] =
                *(const int4*)&tile[xx][cs * 8];
        }
    } else {
        const int i = (blk - 1024) * 256 + t;  // 0..36863
        const int j = i & 7;
        const int l = (i >> 3) & 63;
        const int ot = (i >> 9) & 3;
        const int r = i >> 11;           // 0..17
        const int ks = r % 6, kc = r / 6;
        const int o  = ot * 16 + (l & 15);
        const int kk = ks * 32 + (l >> 4) * 8 + j;
        const int tap = kk >> 6, c = kk & 63;
        const int k = kc * 3 + tap;
        wt[i] = (unsigned short)f32_to_bf16_rne(w[o * CK + c * KK + k]);
    }
}

// Main.  Block = 128 thr = 2 waves; wave owns a 16-px strip x 64 cout,
// wave-private LDS, no __syncthreads.  Chunk-level software pipeline:
//   A(kc+1) params -> bfinish(kc) (waits gathers kc) -> bload(kc+1)
//   (issues 48 gathers) -> C(kc) MFMAs overlap gathers(kc+1) in flight.
// R5 BUG FIX: Plds is now double-buffered by chunk parity — phaseA(kc+1)
// was overwriting the bilinear weights before bfinish(kc) consumed them.
// Mlds stays single-buffered (same-wave LDS ops execute in issue order).
__global__ __launch_bounds__(128, 3) void dcn_main_kernel(
    const float* __restrict__ offset, const float* __restrict__ mask,
    const unsigned short* __restrict__ xt, const unsigned short* __restrict__ wt,
    const float* __restrict__ bias, float* __restrict__ out) {
    __shared__ __align__(16) unsigned short Mlds[2][16 * MROW];  // 2 x 6400 B
    __shared__ __align__(16) int Plds[2][2][48 * 8];             // 2w x 2buf x 1536 B

    const int t    = threadIdx.x;
    const int wave = __builtin_amdgcn_readfirstlane(t >> 6);
    const int lane = t & 63;
    const int quad = lane >> 4, m16 = lane & 15;

    const int blk = blockIdx.x;
    const int xcd = blk & 7;
    const int j   = blk >> 3;                  // 0..255
    const int b   = (xcd << 1) | (j >> 7);     // 2 images per XCD (R2 L2 win)
    const int rr  = j & 127;
    const int row = rr >> 1;
    const int qbase = (rr & 1) * 32 + wave * 16;

    f32x4 acc[4];
#pragma unroll
    for (int ot = 0; ot < 4; ++ot)
#pragma unroll
        for (int r = 0; r < 4; ++r) acc[ot][r] = 0.f;

    const float* offb = offset + b * (2 * KK * HW) + row * 64;
    const float* mb   = mask + b * (KK * HW) + row * 64;
    const char* xtb   = (const char*)(xt + b * (HW * 64));
    char* MW = (char*)Mlds[wave];
    const int co = m16 * 8;          // channel byte offset within a pixel

    uint2 g[12][4];                  // in-flight gather results (96 VGPR)

    auto phaseA = [&](int kc) {
        if (lane < 48) {
            int* PW = Plds[wave][kc & 1];
            const int tap = lane >> 4, pxi = lane & 15;
            const int k = kc * 3 + tap;
            const int q = qbase + pxi;
            const float oy = offb[(2 * k) * HW + q];
            const float ox = offb[(2 * k + 1) * HW + q];
            const float mk = mb[k * HW + q];
            const float py  = oy + (float)(row - 1 + kc);
            const float pxf = ox + (float)(q - 1 + tap);
            const float y0f = floorf(py), x0f = floorf(pxf);
            const float wy = py - y0f, wx = pxf - x0f;
            const int y0 = (int)y0f, x0 = (int)x0f;
            const int y1 = y0 + 1,   x1 = x0 + 1;
            const float vy0 = (y0 >= 0 && y0 < HH) ? 1.f : 0.f;
            const float vy1 = (y1 >= 0 && y1 < HH) ? 1.f : 0.f;
            const float vx0 = (x0 >= 0 && x0 < WW) ? 1.f : 0.f;
            const float vx1 = (x1 >= 0 && x1 < WW) ? 1.f : 0.f;
            const float w00 = (1.f - wy) * (1.f - wx) * vy0 * vx0 * mk;
            const float w01 = (1.f - wy) * wx         * vy0 * vx1 * mk;
            const float w10 = wy * (1.f - wx)         * vy1 * vx0 * mk;
            const float w11 = wy * wx                 * vy1 * vx1 * mk;
            const int cy0 = min(max(y0, 0), HH - 1), cy1 = min(max(y1, 0), HH - 1);
            const int cx0 = min(max(x0, 0), WW - 1), cx1 = min(max(x1, 0), WW - 1);
            int4 P0, P1;
            P0.x = __float_as_int(w00); P0.y = __float_as_int(w01);
            P0.z = __float_as_int(w10); P0.w = __float_as_int(w11);
            P1.x = (cy0 * 64 + cx0) * 128;
            P1.y = (cy0 * 64 + cx1) * 128;
            P1.z = (cy1 * 64 + cx0) * 128;
            P1.w = (cy1 * 64 + cx1) * 128;
            *(int4*)(PW + lane * 8)     = P0;
            *(int4*)(PW + lane * 8 + 4) = P1;
        }
    };

    auto bload = [&](int kc) {
        const int* PW = Plds[wave][kc & 1];
#pragma unroll
        for (int i = 0; i < 12; ++i) {
            const int item = i * 4 + quad;
            const int4 p1 = *(const int4*)(PW + item * 8 + 4);
            g[i][0] = *(const uint2*)(xtb + p1.x + co);
            g[i][1] = *(const uint2*)(xtb + p1.y + co);
            g[i][2] = *(const uint2*)(xtb + p1.z + co);
            g[i][3] = *(const uint2*)(xtb + p1.w + co);
        }
    };

    auto bfinish = [&](int kc) {
        const int* PW = Plds[wave][kc & 1];
#pragma unroll
        for (int i = 0; i < 12; ++i) {
            const int item = i * 4 + quad;
            const int4 p0 = *(const int4*)(PW + item * 8);
            const float fw00 = __int_as_float(p0.x), fw01 = __int_as_float(p0.y);
            const float fw10 = __int_as_float(p0.z), fw11 = __int_as_float(p0.w);
            const uint2 u0 = g[i][0], u1 = g[i][1], u2 = g[i][2], u3 = g[i][3];
            float v0, v1, v2, v3;
            v0 = fw00 * __uint_as_float(u0.x << 16);
            v1 = fw00 * __uint_as_float(u0.x & 0xFFFF0000u);
            v2 = fw00 * __uint_as_float(u0.y << 16);
            v3 = fw00 * __uint_as_float(u0.y & 0xFFFF0000u);
            v0 = fmaf(fw01, __uint_as_float(u1.x << 16), v0);
            v1 = fmaf(fw01, __uint_as_float(u1.x & 0xFFFF0000u), v1);
            v2 = fmaf(fw01, __uint_as_float(u1.y << 16), v2);
            v3 = fmaf(fw01, __uint_as_float(u1.y & 0xFFFF0000u), v3);
            v0 = fmaf(fw10, __uint_as_float(u2.x << 16), v0);
            v1 = fmaf(fw10, __uint_as_float(u2.x & 0xFFFF0000u), v1);
            v2 = fmaf(fw10, __uint_as_float(u2.y << 16), v2);
            v3 = fmaf(fw10, __uint_as_float(u2.y & 0xFFFF0000u), v3);
            v0 = fmaf(fw11, __uint_as_float(u3.x << 16), v0);
            v1 = fmaf(fw11, __uint_as_float(u3.x & 0xFFFF0000u), v1);
            v2 = fmaf(fw11, __uint_as_float(u3.y << 16), v2);
            v3 = fmaf(fw11, __uint_as_float(u3.y & 0xFFFF0000u), v3);
            uint2 pk;
            pk.x = (f32_to_bf16_rne(v1) << 16) | f32_to_bf16_rne(v0);
            pk.y = (f32_to_bf16_rne(v3) << 16) | f32_to_bf16_rne(v2);
            *(uint2*)(MW + (item & 15) * 400 + (item >> 4) * 128 + m16 * 8) = pk;
        }
    };

    auto phaseC = [&](int kc) {
        const unsigned short* wkc = wt + kc * (6 * 4 * 512);
#pragma unroll
        for (int ks = 0; ks < 6; ++ks) {
            const bf16x8 bfrag =
                *(const bf16x8*)(MW + m16 * 400 + ks * 64 + quad * 16);
#pragma unroll
            for (int ot = 0; ot < 4; ++ot) {
                const bf16x8 afrag =
                    *(const bf16x8*)(wkc + (ks * 4 + ot) * 512 + lane * 8);
                acc[ot] = __builtin_amdgcn_mfma_f32_16x16x32_bf16(afrag, bfrag,
                                                                  acc[ot], 0, 0, 0);
            }
        }
    };

    phaseA(0);
    bload(0);
    for (int kc = 0; kc < 3; ++kc) {
        if (kc < 2) phaseA(kc + 1);   // writes Plds[(kc+1)&1] — no clobber now
        bfinish(kc);                  // reads Plds[kc&1] weights, waits gathers
        if (kc < 2) bload(kc + 1);    // issue gathers(kc+1), fly during C(kc)
        phaseC(kc);
    }

    float* ob = out + b * (COUT * HW) + row * 64 + qbase + m16;
#pragma unroll
    for (int ot = 0; ot < 4; ++ot)
#pragma unroll
        for (int r = 0; r < 4; ++r) {
            const int o = ot * 16 + quad * 4 + r;
            ob[o * HW] = acc[ot][r] + bias[o];
        }
}

extern "C" void kernel_launch(void* const* d_in, const int* in_sizes, int n_in,
                              void* d_out, int out_size, void* d_ws,
                              size_t ws_size, hipStream_t stream) {
    const float* x    = (const float*)d_in[0];
    const float* off  = (const float*)d_in[1];
    const float* mask = (const float*)d_in[2];
    const float* w    = (const float*)d_in[3];
    const float* bias = (const float*)d_in[4];
    float* out = (float*)d_out;

    unsigned short* xt = (unsigned short*)d_ws;                     // 8388608 B
    unsigned short* wt = (unsigned short*)((char*)d_ws + 8388608);  // 73728 B

    prep_kernel<<<1024 + 144, 256, 0, stream>>>(x, w, xt, wt);
    dcn_main_kernel<<<2048, 128, 0, stream>>>(off, mask, xt, wt, bias, out);
}

// Round 7
// 112.312 us; speedup vs baseline: 2.5401x; 1.1206x over previous
//
#include <hip/hip_runtime.h>

#define BATCH 16
#define C_IN  64
#define HH    64
#define WW    64
#define COUT  64
#define KK    9
#define HW    4096
#define CK    576
#define MROW  200   // 192 data ushorts + 8 pad; row stride 400 B (16-B aligned)

typedef __bf16 bf16x8 __attribute__((ext_vector_type(8)));
typedef float  f32x4  __attribute__((ext_vector_type(4)));

__device__ __forceinline__ unsigned int f32_to_bf16_rne(float f) {
    unsigned int b = __float_as_uint(f);
    b += 0x7FFFu + ((b >> 16) & 1u);
    return b >> 16;  // low 16 bits valid
}

// Fused prep.  Blocks 0..1023: x (B,C,H,W) f32 -> xt (B,H,W,C) bf16.
// Blocks 1024..1167: w (Cout,C,3,3) f32 -> wt in MFMA A-fragment order:
//   wt[(((kc*6+ks)*4+ot)*64 + lane)*8 + j] = W[o=ot*16+(lane&15)]
//        [kk=ks*32+(lane>>4)*8+j] of chunk kc  (kk = tap*64+c, k=kc*3+tap)
__global__ __launch_bounds__(256) void prep_kernel(
    const float* __restrict__ x, const float* __restrict__ w,
    unsigned short* __restrict__ xt, unsigned short* __restrict__ wt) {
    __shared__ unsigned short tile[64][72];
    const int t = threadIdx.x;
    const int blk = blockIdx.x;
    if (blk < 1024) {
        const int b = blk >> 6, y = blk & 63;
        const float* xrow = x + ((b * 64) * 64 + y) * 64;
#pragma unroll
        for (int it = 0; it < 4; ++it) {
            const int idx = it * 256 + t;
            const int c = idx >> 4, seg = idx & 15;
            const float4 v = *(const float4*)(xrow + c * HW + seg * 4);
            tile[seg * 4 + 0][c] = (unsigned short)f32_to_bf16_rne(v.x);
            tile[seg * 4 + 1][c] = (unsigned short)f32_to_bf16_rne(v.y);
            tile[seg * 4 + 2][c] = (unsigned short)f32_to_bf16_rne(v.z);
            tile[seg * 4 + 3][c] = (unsigned short)f32_to_bf16_rne(v.w);
        }
        __syncthreads();
#pragma unroll
        for (int it = 0; it < 2; ++it) {
            const int idx = it * 256 + t;
            const int xx = idx >> 3, cs = idx & 7;
            *(int4*)&xt[((b * HW) + y * 64 + xx) * 64 + cs * 8] =
                *(const int4*)&tile[xx][cs * 8];
        }
    } else {
        const int i = (blk - 1024) * 256 + t;  // 0..36863
        const int j = i & 7;
        const int l = (i >> 3) & 63;
        const int ot = (i >> 9) & 3;
        const int r = i >> 11;           // 0..17
        const int ks = r % 6, kc = r / 6;
        const int o  = ot * 16 + (l & 15);
        const int kk = ks * 32 + (l >> 4) * 8 + j;
        const int tap = kk >> 6, c = kk & 63;
        const int k = kc * 3 + tap;
        wt[i] = (unsigned short)f32_to_bf16_rne(w[o * CK + c * KK + k]);
    }
}

// Main.  Block = 128 thr = 2 waves; wave owns a 16-px strip x 64 cout,
// wave-private LDS, no __syncthreads.
// R7 changes (theory: L1-miss-throughput bound):
//  1. CU-clustered strip map: blocks landing on the same CU (every 256th
//     blockIdx under round-robin dispatch) cover 8 CONSECUTIVE strips =
//     4 adjacent image rows -> per-CU gather footprint ~48 KB/chunk
//     (was ~190 KB across rows 16 apart) -> ~5x fewer L1 misses.
//  2. All 9 taps' params computed in a prologue into Plds (written once,
//     no loop hazard); addresses packed as u16 pixel indices.
//  3. 48-gather batches pinned with sched_barrier so they genuinely stay
//     in flight (R6: compiler kept only ~12, VGPR=84).
__global__ __launch_bounds__(128, 3) void dcn_main_kernel(
    const float* __restrict__ offset, const float* __restrict__ mask,
    const unsigned short* __restrict__ xt, const unsigned short* __restrict__ wt,
    const float* __restrict__ bias, float* __restrict__ out) {
    __shared__ __align__(16) unsigned short Mlds[2][16 * MROW];  // 12800 B
    __shared__ __align__(16) int PWw[2][144 * 4];                //  4608 B
    __shared__ __align__(8) unsigned short PWa[2][144 * 4];      //  2304 B

    const int t    = threadIdx.x;
    const int wave = __builtin_amdgcn_readfirstlane(t >> 6);
    const int lane = t & 63;
    const int quad = lane >> 4, m16 = lane & 15;

    const int blk = blockIdx.x;
    const int xcd = blk & 7;                    // L2 image pinning (R2 win)
    const int i8  = blk >> 3;                   // 0..255 within XCD
    const int s   = ((i8 & 31) << 3) | (i8 >> 5);  // CU-clustered strip id
    const int b   = (xcd << 1) | (s >> 7);
    const int rr  = s & 127;
    const int row = rr >> 1;
    const int qbase = (rr & 1) * 32 + wave * 16;

    f32x4 acc[4];
#pragma unroll
    for (int ot = 0; ot < 4; ++ot)
#pragma unroll
        for (int r = 0; r < 4; ++r) acc[ot][r] = 0.f;

    const float* offb = offset + b * (2 * KK * HW) + row * 64;
    const float* mb   = mask + b * (KK * HW) + row * 64;
    const char* xtb   = (const char*)(xt + b * (HW * 64));
    char* MW = (char*)Mlds[wave];
    const int co = m16 * 8;          // channel byte offset within a pixel

    // ---- Prologue: params for all 9 taps x 16 px -> PWw/PWa ----
#pragma unroll
    for (int p = 0; p < 3; ++p) {
        if (lane < 48) {
            const int t3  = lane >> 4;          // kx
            const int tap = p * 3 + t3;         // global tap; ky = p
            const int pxi = lane & 15;
            const int q = qbase + pxi;
            const float oy = offb[(2 * tap) * HW + q];
            const float ox = offb[(2 * tap + 1) * HW + q];
            const float mk = mb[tap * HW + q];
            const float py  = oy + (float)(row - 1 + p);
            const float pxf = ox + (float)(q - 1 + t3);
            const float y0f = floorf(py), x0f = floorf(pxf);
            const float wy = py - y0f, wx = pxf - x0f;
            const int y0 = (int)y0f, x0 = (int)x0f;
            const int y1 = y0 + 1,   x1 = x0 + 1;
            const float vy0 = (y0 >= 0 && y0 < HH) ? 1.f : 0.f;
            const float vy1 = (y1 >= 0 && y1 < HH) ? 1.f : 0.f;
            const float vx0 = (x0 >= 0 && x0 < WW) ? 1.f : 0.f;
            const float vx1 = (x1 >= 0 && x1 < WW) ? 1.f : 0.f;
            const float w00 = (1.f - wy) * (1.f - wx) * vy0 * vx0 * mk;
            const float w01 = (1.f - wy) * wx         * vy0 * vx1 * mk;
            const float w10 = wy * (1.f - wx)         * vy1 * vx0 * mk;
            const float w11 = wy * wx                 * vy1 * vx1 * mk;
            const int cy0 = min(max(y0, 0), HH - 1), cy1 = min(max(y1, 0), HH - 1);
            const int cx0 = min(max(x0, 0), WW - 1), cx1 = min(max(x1, 0), WW - 1);
            const int it = tap * 16 + pxi;
            int4 P0;
            P0.x = __float_as_int(w00); P0.y = __float_as_int(w01);
            P0.z = __float_as_int(w10); P0.w = __float_as_int(w11);
            *(int4*)&PWw[wave][it * 4] = P0;
            ushort4 A;
            A.x = (unsigned short)(cy0 * 64 + cx0);
            A.y = (unsigned short)(cy0 * 64 + cx1);
            A.z = (unsigned short)(cy1 * 64 + cx0);
            A.w = (unsigned short)(cy1 * 64 + cx1);
            *(ushort4*)&PWa[wave][it * 4] = A;
        }
    }

    uint2 g[12][4];                  // 48 in-flight gathers (96 VGPR)

    auto bload = [&](int kc) {
        const unsigned short* Pa = &PWa[wave][0] + 48 * kc * 4;
#pragma unroll
        for (int i = 0; i < 12; ++i) {
            const int l = i * 4 + quad;
            const ushort4 a = *(const ushort4*)(Pa + l * 4);
            g[i][0] = *(const uint2*)(xtb + ((int)a.x << 7) + co);
            g[i][1] = *(const uint2*)(xtb + ((int)a.y << 7) + co);
            g[i][2] = *(const uint2*)(xtb + ((int)a.z << 7) + co);
            g[i][3] = *(const uint2*)(xtb + ((int)a.w << 7) + co);
        }
    };

    auto bfinish = [&](int kc) {
        const int* Pw = &PWw[wave][0] + 48 * kc * 4;
#pragma unroll
        for (int i = 0; i < 12; ++i) {
            const int l = i * 4 + quad;
            const int4 p0 = *(const int4*)(Pw + l * 4);
            const float fw00 = __int_as_float(p0.x), fw01 = __int_as_float(p0.y);
            const float fw10 = __int_as_float(p0.z), fw11 = __int_as_float(p0.w);
            const uint2 u0 = g[i][0], u1 = g[i][1], u2 = g[i][2], u3 = g[i][3];
            float v0, v1, v2, v3;
            v0 = fw00 * __uint_as_float(u0.x << 16);
            v1 = fw00 * __uint_as_float(u0.x & 0xFFFF0000u);
            v2 = fw00 * __uint_as_float(u0.y << 16);
            v3 = fw00 * __uint_as_float(u0.y & 0xFFFF0000u);
            v0 = fmaf(fw01, __uint_as_float(u1.x << 16), v0);
            v1 = fmaf(fw01, __uint_as_float(u1.x & 0xFFFF0000u), v1);
            v2 = fmaf(fw01, __uint_as_float(u1.y << 16), v2);
            v3 = fmaf(fw01, __uint_as_float(u1.y & 0xFFFF0000u), v3);
            v0 = fmaf(fw10, __uint_as_float(u2.x << 16), v0);
            v1 = fmaf(fw10, __uint_as_float(u2.x & 0xFFFF0000u), v1);
            v2 = fmaf(fw10, __uint_as_float(u2.y << 16), v2);
            v3 = fmaf(fw10, __uint_as_float(u2.y & 0xFFFF0000u), v3);
            v0 = fmaf(fw11, __uint_as_float(u3.x << 16), v0);
            v1 = fmaf(fw11, __uint_as_float(u3.x & 0xFFFF0000u), v1);
            v2 = fmaf(fw11, __uint_as_float(u3.y << 16), v2);
            v3 = fmaf(fw11, __uint_as_float(u3.y & 0xFFFF0000u), v3);
            uint2 pk;
            pk.x = (f32_to_bf16_rne(v1) << 16) | f32_to_bf16_rne(v0);
            pk.y = (f32_to_bf16_rne(v3) << 16) | f32_to_bf16_rne(v2);
            *(uint2*)(MW + (l & 15) * 400 + (l >> 4) * 128 + m16 * 8) = pk;
        }
    };

    auto phaseC = [&](int kc) {
        const unsigned short* wkc = wt + kc * (6 * 4 * 512);
#pragma unroll
        for (int ks = 0; ks < 6; ++ks) {
            const bf16x8 bfrag =
                *(const bf16x8*)(MW + m16 * 400 + ks * 64 + quad * 16);
#pragma unroll
            for (int ot = 0; ot < 4; ++ot) {
                const bf16x8 afrag =
                    *(const bf16x8*)(wkc + (ks * 4 + ot) * 512 + lane * 8);
                acc[ot] = __builtin_amdgcn_mfma_f32_16x16x32_bf16(afrag, bfrag,
                                                                  acc[ot], 0, 0, 0);
            }
        }
    };

    bload(0);
    __builtin_amdgcn_sched_barrier(0);   // keep all 48 issued before use
    for (int kc = 0; kc < 3; ++kc) {
        bfinish(kc);
        if (kc < 2) {
            bload(kc + 1);
            __builtin_amdgcn_sched_barrier(0);
        }
        phaseC(kc);
    }

    float* ob = out + b * (COUT * HW) + row * 64 + qbase + m16;
#pragma unroll
    for (int ot = 0; ot < 4; ++ot)
#pragma unroll
        for (int r = 0; r < 4; ++r) {
            const int o = ot * 16 + quad * 4 + r;
            ob[o * HW] = acc[ot][r] + bias[o];
        }
}

extern "C" void kernel_launch(void* const* d_in, const int* in_sizes, int n_in,
                              void* d_out, int out_size, void* d_ws,
                              size_t ws_size, hipStream_t stream) {
    const float* x    = (const float*)d_in[0];
    const float* off  = (const float*)d_in[1];
    const float* mask = (const float*)d_in[2];
    const float* w    = (const float*)d_in[3];
    const float* bias = (const float*)d_in[4];
    float* out = (float*)d_out;

    unsigned short* xt = (unsigned short*)d_ws;                     // 8388608 B
    unsigned short* wt = (unsigned short*)((char*)d_ws + 8388608);  // 73728 B

    prep_kernel<<<1024 + 144, 256, 0, stream>>>(x, w, xt, wt);
    dcn_main_kernel<<<2048, 128, 0, stream>>>(off, mask, xt, wt, bias, out);
}